// Round 5
// baseline (279.456 us; speedup 1.0000x reference)
//
#include <hip/hip_runtime.h>

typedef unsigned short ushort_t;
typedef __bf16 bf16x8 __attribute__((ext_vector_type(8)));
typedef float floatx4 __attribute__((ext_vector_type(4)));

#define B_ 8
#define N_ 8192
#define S_ 2048
#define D1_ 128
#define D2_ 256
#define INCH_ 384
#define M_ 65536  // B*N

// async global->LDS, 16B per lane; LDS dest = wave-uniform base + lane*16
#define ASYNC_CP16(g, l)                                                  \
  __builtin_amdgcn_global_load_lds(                                       \
      (const __attribute__((address_space(1))) void*)(g),                 \
      (__attribute__((address_space(3))) void*)(l), 16, 0, 0)

// ---------- workspace layout (bytes) ----------
constexpr size_t OFF_STATS = 0;          // 6144 B used
constexpr size_t OFF_W0B   = 8192;       // 256*384*2 = 196608
constexpr size_t OFF_W1B   = 204800;     // 128*256*2 = 65536
constexpr size_t OFF_X2P   = 270336;     // 8*2048*16 = 262144 (float4 x,y,z,0.5*|x|^2)
constexpr size_t OFF_P2T   = 532480;     // 8*2048*256*2 = 8388608 bf16
constexpr size_t OFF_XC    = 8921088;    // 65536*384*2 = 50331648 bf16 ; Y2t overlays after GEMM1
constexpr size_t OFF_Y1    = 59252736;   // 65536*256*2 = 33554432 bf16

// native bf16 convert: lowers to v_cvt_pk_bf16_f32 (1 op vs 5 manual; RNE both)
__device__ __forceinline__ ushort_t f2bf(float f) {
  __bf16 h = (__bf16)f;
  union { __bf16 h; ushort_t u; } v;
  v.h = h;
  return v.u;
}
__device__ __forceinline__ float bf2f(ushort_t h) {
  return __uint_as_float(((unsigned int)h) << 16);
}

// insert (e,s) into sorted top-3 (c0<=c1<=c2); strict < keeps incumbent on ties
__device__ __forceinline__ void ins3(float e, int s,
                                     float& c0, float& c1, float& c2,
                                     int& i0, int& i1, int& i2) {
  bool l0 = e < c0, l1 = e < c1, l2 = e < c2;
  float nf0 = fminf(e, c0);
  float nf1 = __builtin_amdgcn_fmed3f(e, c0, c1);
  float nf2 = __builtin_amdgcn_fmed3f(e, c1, c2);
  i2 = l1 ? i1 : (l2 ? s : i2);
  i1 = l0 ? i0 : (l1 ? s : i1);
  i0 = l0 ? s : i0;
  c0 = nf0; c1 = nf1; c2 = nf2;
}

// ---------- prep: weights fp32->bf16 + pack xyz2 (one launch) ----------
__global__ __launch_bounds__(256) void k_prep(const float* __restrict__ W0,
                                              const float* __restrict__ W1,
                                              const float* __restrict__ xyz2,
                                              ushort_t* __restrict__ W0b,
                                              ushort_t* __restrict__ W1b,
                                              float4* __restrict__ x2p) {
  int i = blockIdx.x * 256 + threadIdx.x;  // grid 576
  if (i < 98304) {
    W0b[i] = f2bf(W0[i]);
  } else if (i < 131072) {
    W1b[i - 98304] = f2bf(W1[i - 98304]);
  } else {
    int idx = i - 131072;  // 16384
    int b = idx >> 11, s = idx & (S_ - 1);
    const float* base = xyz2 + (size_t)b * 3 * S_;
    float x = base[s], y = base[S_ + s], z = base[2 * S_ + s];
    x2p[idx] = make_float4(x, y, z, 0.5f * (x * x + y * y + z * z));
  }
}

// ---------- transpose points2 [B,256,S] -> p2t bf16 [B,S,256] ----------
__global__ void k_tr_p2(const float* __restrict__ P2, ushort_t* __restrict__ p2t) {
  __shared__ float t[32][33];
  int b = blockIdx.z;
  int s0 = blockIdx.x * 32;
  int c0 = blockIdx.y * 32;
  int tx = threadIdx.x, ty = threadIdx.y;  // (32,8)
#pragma unroll
  for (int j = 0; j < 4; j++) {
    int c = c0 + ty + j * 8;
    t[ty + j * 8][tx] = P2[((size_t)b * D2_ + c) * S_ + s0 + tx];
  }
  __syncthreads();
#pragma unroll
  for (int j = 0; j < 4; j++) {
    int s = s0 + ty + j * 8;
    p2t[((size_t)b * S_ + s) * D2_ + c0 + tx] = f2bf(t[tx][ty + j * 8]);
  }
}

// ---------- transpose points1 [B,128,N] -> Xc cols 0..127 (bf16, row stride 384) ----------
__global__ void k_tr_p1(const float* __restrict__ P1, ushort_t* __restrict__ Xc) {
  __shared__ float t[32][33];
  int b = blockIdx.z;
  int n0 = blockIdx.x * 32;
  int c0 = blockIdx.y * 32;
  int tx = threadIdx.x, ty = threadIdx.y;
#pragma unroll
  for (int j = 0; j < 4; j++) {
    int c = c0 + ty + j * 8;
    t[ty + j * 8][tx] = P1[((size_t)b * D1_ + c) * N_ + n0 + tx];
  }
  __syncthreads();
#pragma unroll
  for (int j = 0; j < 4; j++) {
    int n = n0 + ty + j * 8;
    Xc[((size_t)b * N_ + n) * INCH_ + c0 + tx] = f2bf(t[tx][ty + j * 8]);
  }
}

// ---------- kNN + interpolate: 1024 blocks x 512 threads, 64 queries/block ----------
// Hot loop: packed top-4 keys (f32 d, low 8 mantissa bits = chunk-local idx);
// sorted insert = 4 min/med3, no cmps. Exact recompute + exact ins3 merge after.
__global__ __launch_bounds__(512, 8) void k_knn(const float* __restrict__ xyz1,
                                                const float4* __restrict__ x2p,
                                                const ushort_t* __restrict__ p2t,
                                                ushort_t* __restrict__ Xc) {
  __shared__ float4 xs[8 * 289];     // 36992 B, chunk c at xs + c*289
  __shared__ float wsh[64 * 3];
  __shared__ int   ish[64 * 3];
  int t = threadIdx.x;
  int q0 = blockIdx.x * 64;
  int b = q0 >> 13;
  int n0 = q0 & (N_ - 1);
  for (int l = t; l < S_; l += 512)
    xs[(l >> 8) * 289 + (l & 255)] = x2p[(size_t)b * S_ + l];
  int sub = t & 7;
  int qg = t >> 3;  // [0,64)
  int n = n0 + qg;
  float qx = xyz1[((size_t)b * 3 + 0) * N_ + n];
  float qy = xyz1[((size_t)b * 3 + 1) * N_ + n];
  float qz = xyz1[((size_t)b * 3 + 2) * N_ + n];
  float nrm1 = qx * qx + qy * qy + qz * qz;
  __syncthreads();
  const float4* bp = xs + sub * 289;
  float k0 = 3e38f, k1 = 3e38f, k2 = 3e38f, k3 = 3e38f;
#pragma unroll 4
  for (int i = 0; i < 256; ++i) {
    float4 P = bp[i];
    float e = fmaf(-qx, P.x, fmaf(-qy, P.y, fmaf(-qz, P.z, P.w)));
    float dd = fmaf(2.f, e, nrm1);
    unsigned int kb = (__float_as_uint(dd) & 0xFFFFFF00u) | (unsigned int)i;
    float k = __uint_as_float(kb);
    float n0_ = fminf(k, k0);
    float n1_ = __builtin_amdgcn_fmed3f(k, k0, k1);
    float n2_ = __builtin_amdgcn_fmed3f(k, k1, k2);
    float n3_ = __builtin_amdgcn_fmed3f(k, k2, k3);
    k0 = n0_; k1 = n1_; k2 = n2_; k3 = n3_;
  }
  float ed[4];
  int   si[4];
  {
    float kk[4] = {k0, k1, k2, k3};
#pragma unroll
    for (int c = 0; c < 4; ++c) {
      int loc = (int)(__float_as_uint(kk[c]) & 255u);
      float4 P = bp[loc];
      float e = fmaf(-qx, P.x, fmaf(-qy, P.y, fmaf(-qz, P.z, P.w)));
      ed[c] = fmaf(2.f, e, nrm1);
      si[c] = (sub << 8) + loc;
    }
  }
  float c0 = 3e38f, c1 = 3e38f, c2 = 3e38f;
  int i0 = 0, i1 = 0, i2 = 0;
#pragma unroll
  for (int c = 0; c < 4; ++c) ins3(ed[c], si[c], c0, c1, c2, i0, i1, i2);
#pragma unroll
  for (int d = 1; d < 8; d <<= 1) {
    float e0 = __shfl_xor(c0, d); int s0 = __shfl_xor(i0, d);
    float e1 = __shfl_xor(c1, d); int s1 = __shfl_xor(i1, d);
    float e2 = __shfl_xor(c2, d); int s2 = __shfl_xor(i2, d);
    ins3(e0, s0, c0, c1, c2, i0, i1, i2);
    ins3(e1, s1, c0, c1, c2, i0, i1, i2);
    ins3(e2, s2, c0, c1, c2, i0, i1, i2);
  }
  if (sub == 0) {
    float r0 = 1.f / (c0 + 1e-8f);
    float r1 = 1.f / (c1 + 1e-8f);
    float r2 = 1.f / (c2 + 1e-8f);
    float rs = 1.f / (r0 + r1 + r2);
    wsh[qg * 3 + 0] = r0 * rs; wsh[qg * 3 + 1] = r1 * rs; wsh[qg * 3 + 2] = r2 * rs;
    ish[qg * 3 + 0] = i0; ish[qg * 3 + 1] = i1; ish[qg * 3 + 2] = i2;
  }
  __syncthreads();
  int lane = t & 63, grp = t >> 6;
  size_t sbase2 = (size_t)b * S_;
#pragma unroll 2
  for (int it = 0; it < 8; ++it) {
    int ql = it * 8 + grp;
    int q = q0 + ql;
    float w0 = wsh[ql * 3 + 0], w1 = wsh[ql * 3 + 1], w2 = wsh[ql * 3 + 2];
    int j0 = ish[ql * 3 + 0], j1 = ish[ql * 3 + 1], j2 = ish[ql * 3 + 2];
    ushort4 a0 = *(const ushort4*)&p2t[(sbase2 + j0) * D2_ + lane * 4];
    ushort4 a1 = *(const ushort4*)&p2t[(sbase2 + j1) * D2_ + lane * 4];
    ushort4 a2 = *(const ushort4*)&p2t[(sbase2 + j2) * D2_ + lane * 4];
    ushort4 o;
    o.x = f2bf(w0 * bf2f(a0.x) + w1 * bf2f(a1.x) + w2 * bf2f(a2.x));
    o.y = f2bf(w0 * bf2f(a0.y) + w1 * bf2f(a1.y) + w2 * bf2f(a2.y));
    o.z = f2bf(w0 * bf2f(a0.z) + w1 * bf2f(a1.z) + w2 * bf2f(a2.z));
    o.w = f2bf(w0 * bf2f(a0.w) + w1 * bf2f(a1.w) + w2 * bf2f(a2.w));
    *(ushort4*)&Xc[(size_t)q * INCH_ + D1_ + lane * 4] = o;
  }
}

// ---------- GEMM1: Y1b[M,256](bf16) = Xc[M,384] * W0b[256,384]^T, 128x256 tile ----------
__global__ __launch_bounds__(512) void k_gemm1(const ushort_t* __restrict__ A,
                                               const ushort_t* __restrict__ Bw,
                                               ushort_t* __restrict__ Cc,
                                               float* __restrict__ sum,
                                               float* __restrict__ ssq) {
  __shared__ __align__(16) ushort_t As[128 * 32];
  __shared__ __align__(16) ushort_t Bs[256 * 32];
  const int tid = threadIdx.x;
  const int m0 = blockIdx.x * 128;
  const int wave = tid >> 6;
  const int wuni = __builtin_amdgcn_readfirstlane(wave);  // 0..7
  const int lane = tid & 63;
  const int quad = lane >> 4;
  const int l16 = lane & 15;
  const int wrow = (wave >> 2) * 64;   // 2 row-waves
  const int wcol = (wave & 3) * 64;    // 4 col-waves
  const int arow = tid >> 2, aseg = tid & 3;
  floatx4 acc[4][4];
#pragma unroll
  for (int i = 0; i < 4; i++)
#pragma unroll
    for (int j = 0; j < 4; j++) acc[i][j] = (floatx4){0.f, 0.f, 0.f, 0.f};

  for (int k0 = 0; k0 < INCH_; k0 += 32) {
    ASYNC_CP16(&A[(size_t)(m0 + arow) * INCH_ + k0 + aseg * 8], &As[wuni * 512]);
#pragma unroll
    for (int it = 0; it < 2; it++) {
      int l = tid + it * 512;
      int row = l >> 2, seg = l & 3;
      ASYNC_CP16(&Bw[(size_t)row * INCH_ + k0 + seg * 8], &Bs[it * 4096 + wuni * 512]);
    }
    __syncthreads();
    bf16x8 af[4], bfr[4];
#pragma unroll
    for (int mt = 0; mt < 4; mt++) af[mt] = *(const bf16x8*)&As[(wrow + mt * 16 + l16) * 32 + quad * 8];
#pragma unroll
    for (int nt = 0; nt < 4; nt++) bfr[nt] = *(const bf16x8*)&Bs[(wcol + nt * 16 + l16) * 32 + quad * 8];
#pragma unroll
    for (int mt = 0; mt < 4; mt++)
#pragma unroll
      for (int nt = 0; nt < 4; nt++)
        acc[mt][nt] = __builtin_amdgcn_mfma_f32_16x16x32_bf16(af[mt], bfr[nt], acc[mt][nt], 0, 0, 0);
    __syncthreads();
  }
#pragma unroll
  for (int mt = 0; mt < 4; mt++) {
#pragma unroll
    for (int i = 0; i < 4; i++) {
      int row = m0 + wrow + mt * 16 + quad * 4 + i;
#pragma unroll
      for (int nt = 0; nt < 4; nt++) {
        int col = wcol + nt * 16 + l16;
        Cc[(size_t)row * 256 + col] = f2bf(acc[mt][nt][i]);
      }
    }
  }
#pragma unroll
  for (int nt = 0; nt < 4; nt++) {
    float s = 0.f, s2 = 0.f;
#pragma unroll
    for (int mt = 0; mt < 4; mt++)
#pragma unroll
      for (int i = 0; i < 4; i++) {
        float v = acc[mt][nt][i];
        s += v;
        s2 = fmaf(v, v, s2);
      }
    s += __shfl_xor(s, 16);  s2 += __shfl_xor(s2, 16);
    s += __shfl_xor(s, 32);  s2 += __shfl_xor(s2, 32);
    if (quad == 0) {
      int col = wcol + nt * 16 + l16;
      atomicAdd(&sum[col], s);
      atomicAdd(&ssq[col], s2);
    }
  }
}

// ---------- GEMM2 + BN1 stats + TRANSPOSED Y2 write ----------
// 1024 blocks x 256 thr, 64x128 tile, 4 waves (2 row x 2 col, each 32x64).
// Writes Y2t[b*128+c][n] bf16 so the finalize kernel is pure streaming.
__global__ __launch_bounds__(256, 4) void k_gemm2t(const ushort_t* __restrict__ Y1,
                                                   const ushort_t* __restrict__ Bw,
                                                   const float* __restrict__ sum0,
                                                   const float* __restrict__ ssq0,
                                                   const float* __restrict__ g0,
                                                   const float* __restrict__ be0,
                                                   ushort_t* __restrict__ Y2t,
                                                   float* __restrict__ sum1,
                                                   float* __restrict__ ssq1) {
  // union: GEMM staging (As 4K + Bs 8K) overlaid with transpose buf tb[64][129] f32
  __shared__ __align__(16) char ubuf[64 * 129 * 4];  // 33024 B
  __shared__ float scs[256], shs[256];
  ushort_t* As = (ushort_t*)ubuf;
  ushort_t* Bs = (ushort_t*)(ubuf + 4096);
  float* tb = (float*)ubuf;
  const int tid = threadIdx.x;
  const int m0 = blockIdx.x * 64;
  const int b = m0 >> 13;
  const int n0 = m0 & (N_ - 1);
  const int wave = tid >> 6;
  const int wuni = __builtin_amdgcn_readfirstlane(wave);  // 0..3
  const int lane = tid & 63;
  const int quad = lane >> 4;
  const int l16 = lane & 15;
  const int wrow = (wave >> 1) * 32;   // 2 row-waves of 32
  const int wcol = (wave & 1) * 64;    // 2 col-waves of 64
  {
    float mean = sum0[tid] * (1.f / 65536.f);
    float var = ssq0[tid] * (1.f / 65536.f) - mean * mean;
    float sc = rsqrtf(var + 1e-5f) * g0[tid];
    scs[tid] = sc;
    shs[tid] = be0[tid] - mean * sc;
  }
  floatx4 acc[2][4];
#pragma unroll
  for (int i = 0; i < 2; i++)
#pragma unroll
    for (int j = 0; j < 4; j++) acc[i][j] = (floatx4){0.f, 0.f, 0.f, 0.f};
  __syncthreads();

  const int arow = tid >> 2, aseg = tid & 3;  // A: 64 rows x 4 segs
  for (int k0 = 0; k0 < 256; k0 += 32) {
    // B tile async: 128x32 = 512 lane-loads (2 its)
#pragma unroll
    for (int it = 0; it < 2; it++) {
      int l = tid + it * 256;
      int row = l >> 2, seg = l & 3;
      ASYNC_CP16(&Bw[(size_t)row * 256 + k0 + seg * 8], &Bs[it * 2048 + wuni * 512]);
    }
    // A tile: BN0+relu transform on the fly (64 rows x 32 k)
    {
      ushort4 y01 = *(const ushort4*)&Y1[(size_t)(m0 + arow) * 256 + k0 + aseg * 8];
      ushort4 y23 = *(const ushort4*)&Y1[(size_t)(m0 + arow) * 256 + k0 + aseg * 8 + 4];
      int c = k0 + aseg * 8;
      ushort4 o0, o1;
      o0.x = f2bf(fmaxf(fmaf(bf2f(y01.x), scs[c + 0], shs[c + 0]), 0.f));
      o0.y = f2bf(fmaxf(fmaf(bf2f(y01.y), scs[c + 1], shs[c + 1]), 0.f));
      o0.z = f2bf(fmaxf(fmaf(bf2f(y01.z), scs[c + 2], shs[c + 2]), 0.f));
      o0.w = f2bf(fmaxf(fmaf(bf2f(y01.w), scs[c + 3], shs[c + 3]), 0.f));
      o1.x = f2bf(fmaxf(fmaf(bf2f(y23.x), scs[c + 4], shs[c + 4]), 0.f));
      o1.y = f2bf(fmaxf(fmaf(bf2f(y23.y), scs[c + 5], shs[c + 5]), 0.f));
      o1.z = f2bf(fmaxf(fmaf(bf2f(y23.z), scs[c + 6], shs[c + 6]), 0.f));
      o1.w = f2bf(fmaxf(fmaf(bf2f(y23.w), scs[c + 7], shs[c + 7]), 0.f));
      *(ushort4*)&As[arow * 32 + aseg * 8] = o0;
      *(ushort4*)&As[arow * 32 + aseg * 8 + 4] = o1;
    }
    __syncthreads();
    bf16x8 af[2], bfr[4];
#pragma unroll
    for (int mt = 0; mt < 2; mt++) af[mt] = *(const bf16x8*)&As[(wrow + mt * 16 + l16) * 32 + quad * 8];
#pragma unroll
    for (int nt = 0; nt < 4; nt++) bfr[nt] = *(const bf16x8*)&Bs[(wcol + nt * 16 + l16) * 32 + quad * 8];
#pragma unroll
    for (int mt = 0; mt < 2; mt++)
#pragma unroll
      for (int nt = 0; nt < 4; nt++)
        acc[mt][nt] = __builtin_amdgcn_mfma_f32_16x16x32_bf16(af[mt], bfr[nt], acc[mt][nt], 0, 0, 0);
    __syncthreads();
  }
  // BN1 stats from f32 acc (each wave covers 32 rows x 64 cols)
#pragma unroll
  for (int nt = 0; nt < 4; nt++) {
    float s = 0.f, s2 = 0.f;
#pragma unroll
    for (int mt = 0; mt < 2; mt++)
#pragma unroll
      for (int i = 0; i < 4; i++) {
        float v = acc[mt][nt][i];
        s += v;
        s2 = fmaf(v, v, s2);
      }
    s += __shfl_xor(s, 16);  s2 += __shfl_xor(s2, 16);
    s += __shfl_xor(s, 32);  s2 += __shfl_xor(s2, 32);
    if (quad == 0) {
      int col = wcol + nt * 16 + l16;
      atomicAdd(&sum1[col], s);
      atomicAdd(&ssq1[col], s2);
    }
  }
  // stage raw acc f32 -> tb (4 waves, disjoint 32x64 regions)
#pragma unroll
  for (int mt = 0; mt < 2; mt++)
#pragma unroll
    for (int i = 0; i < 4; i++) {
      int rl = wrow + mt * 16 + quad * 4 + i;  // 0..63
#pragma unroll
      for (int nt = 0; nt < 4; nt++) {
        int col = wcol + nt * 16 + l16;
        tb[rl * 129 + col] = acc[mt][nt][i];
      }
    }
  __syncthreads();
  // transposed write: Y2t[(b*128+c)*N + n0 + j], ushort4 (4 n's per store)
#pragma unroll
  for (int it = 0; it < 8; ++it) {
    int idx = it * 256 + tid;        // [0,2048)
    int c = idx >> 4;                // channel 0..127
    int j4 = (idx & 15) * 4;         // n offset 0..60
    ushort4 v;
    v.x = f2bf(tb[(j4 + 0) * 129 + c]);
    v.y = f2bf(tb[(j4 + 1) * 129 + c]);
    v.z = f2bf(tb[(j4 + 2) * 129 + c]);
    v.w = f2bf(tb[(j4 + 3) * 129 + c]);
    *(ushort4*)&Y2t[((size_t)(b * 128 + c)) * N_ + n0 + j4] = v;
  }
}

// ---------- finalize: BN1 + relu, pure streaming (Y2t bf16 -> out f32) ----------
__global__ __launch_bounds__(256) void k_out2(const ushort_t* __restrict__ Y2t,
                                              const float* __restrict__ sum1,
                                              const float* __restrict__ ssq1,
                                              const float* __restrict__ g1,
                                              const float* __restrict__ be1,
                                              float* __restrict__ out) {
  __shared__ float sc1[128], sh1[128];
  int tid = threadIdx.x;
  if (tid < 128) {
    float mean = sum1[tid] * (1.f / 65536.f);
    float var = ssq1[tid] * (1.f / 65536.f) - mean * mean;
    float sc = rsqrtf(var + 1e-5f) * g1[tid];
    sc1[tid] = sc;
    sh1[tid] = be1[tid] - mean * sc;
  }
  __syncthreads();
  // 2048 blocks x 256 thr x 4 its of float4 = 8 rows*... total 2,097,152 float4
#pragma unroll
  for (int it = 0; it < 4; ++it) {
    int fid = (it * 2048 + blockIdx.x) * 256 + tid;   // [0, 2^21)
    int r = fid >> 11;            // row 0..1023 (b*128+c)
    int c = r & 127;
    int n4 = (fid & 2047) * 4;
    ushort4 y = *(const ushort4*)&Y2t[((size_t)r << 13) + n4];
    float sc = sc1[c], sh = sh1[c];
    float4 v;
    v.x = fmaxf(fmaf(bf2f(y.x), sc, sh), 0.f);
    v.y = fmaxf(fmaf(bf2f(y.y), sc, sh), 0.f);
    v.z = fmaxf(fmaf(bf2f(y.z), sc, sh), 0.f);
    v.w = fmaxf(fmaf(bf2f(y.w), sc, sh), 0.f);
    *(float4*)&out[((size_t)r << 13) + n4] = v;
  }
}

extern "C" void kernel_launch(void* const* d_in, const int* in_sizes, int n_in,
                              void* d_out, int out_size, void* d_ws, size_t ws_size,
                              hipStream_t stream) {
  const float* xyz1    = (const float*)d_in[0];
  const float* xyz2    = (const float*)d_in[1];
  const float* points1 = (const float*)d_in[2];
  const float* points2 = (const float*)d_in[3];
  const float* W0 = (const float*)d_in[4];
  const float* g0 = (const float*)d_in[6];
  const float* be0 = (const float*)d_in[7];
  const float* W1 = (const float*)d_in[8];
  const float* g1 = (const float*)d_in[10];
  const float* be1 = (const float*)d_in[11];
  float* out = (float*)d_out;
  char* ws = (char*)d_ws;

  float* sum0   = (float*)(ws + OFF_STATS);
  float* ssq0   = sum0 + 256;
  float* sum1   = sum0 + 512;
  float* ssq1   = sum0 + 640;
  ushort_t* W0b = (ushort_t*)(ws + OFF_W0B);
  ushort_t* W1b = (ushort_t*)(ws + OFF_W1B);
  float4* x2p   = (float4*)(ws + OFF_X2P);
  ushort_t* p2t = (ushort_t*)(ws + OFF_P2T);
  ushort_t* Xc  = (ushort_t*)(ws + OFF_XC);
  ushort_t* Y1b = (ushort_t*)(ws + OFF_Y1);
  ushort_t* Y2t = (ushort_t*)(ws + OFF_XC);  // overlays Xc (dead after GEMM1)

  hipMemsetAsync(ws + OFF_STATS, 0, 6144, stream);
  k_prep<<<576, 256, 0, stream>>>(W0, W1, xyz2, W0b, W1b, x2p);
  k_tr_p2<<<dim3(64, 8, 8), dim3(32, 8), 0, stream>>>(points2, p2t);
  k_tr_p1<<<dim3(256, 4, 8), dim3(32, 8), 0, stream>>>(points1, Xc);
  k_knn<<<1024, 512, 0, stream>>>(xyz1, x2p, p2t, Xc);
  k_gemm1<<<512, 512, 0, stream>>>(Xc, W0b, Y1b, sum0, ssq0);
  k_gemm2t<<<1024, 256, 0, stream>>>(Y1b, W1b, sum0, ssq0, g0, be0,
                                     Y2t, sum1, ssq1);
  k_out2<<<2048, 256, 0, stream>>>(Y2t, sum1, ssq1, g1, be1, out);
}

// Round 6
// 217.293 us; speedup vs baseline: 1.2861x; 1.2861x over previous
//
#include <hip/hip_runtime.h>

typedef unsigned short ushort_t;
typedef __bf16 bf16x8 __attribute__((ext_vector_type(8)));
typedef float floatx4 __attribute__((ext_vector_type(4)));

#define B_ 8
#define N_ 8192
#define S_ 2048
#define D1_ 128
#define D2_ 256
#define INCH_ 384
#define M_ 65536  // B*N

// async global->LDS, 16B per lane; LDS dest = wave-uniform base + lane*16
#define ASYNC_CP16(g, l)                                                  \
  __builtin_amdgcn_global_load_lds(                                       \
      (const __attribute__((address_space(1))) void*)(g),                 \
      (__attribute__((address_space(3))) void*)(l), 16, 0, 0)

// ---------- workspace layout (bytes) ----------
constexpr size_t OFF_STATS = 0;          // 6144 B used (final sums)
constexpr size_t OFF_W0B   = 8192;       // 256*384*2 = 196608
constexpr size_t OFF_W1B   = 204800;     // 128*256*2 = 65536
constexpr size_t OFF_X2P   = 270336;     // 8*2048*16 = 262144 (float4 x,y,z,0.5*|x|^2)
constexpr size_t OFF_P2T   = 532480;     // 8*2048*256*2 = 8388608 bf16 (dead after k_knn)
constexpr size_t OFF_XC    = 8921088;    // 65536*384*2 = 50331648 bf16 ; Y2t overlays after GEMM1
constexpr size_t OFF_Y1    = 59252736;   // 65536*256*2 = 33554432 bf16
// BN-stat partials overlay the dead p2t region (gemm kernels run after k_knn):
constexpr size_t OFF_PS0   = OFF_P2T;             // 512 blk x 256 col x 4B = 512K
constexpr size_t OFF_PQ0   = OFF_P2T + 524288;    // 512K
constexpr size_t OFF_PS1   = OFF_P2T + 1048576;   // 1024 blk x 128 col x 4B = 512K
constexpr size_t OFF_PQ1   = OFF_P2T + 1572864;   // 512K

// native bf16 convert: lowers to v_cvt_pk_bf16_f32 (1 op vs 5 manual; RNE both)
__device__ __forceinline__ ushort_t f2bf(float f) {
  __bf16 h = (__bf16)f;
  union { __bf16 h; ushort_t u; } v;
  v.h = h;
  return v.u;
}
__device__ __forceinline__ float bf2f(ushort_t h) {
  return __uint_as_float(((unsigned int)h) << 16);
}

// insert (e,s) into sorted top-3 (c0<=c1<=c2); strict < keeps incumbent on ties
__device__ __forceinline__ void ins3(float e, int s,
                                     float& c0, float& c1, float& c2,
                                     int& i0, int& i1, int& i2) {
  bool l0 = e < c0, l1 = e < c1, l2 = e < c2;
  float nf0 = fminf(e, c0);
  float nf1 = __builtin_amdgcn_fmed3f(e, c0, c1);
  float nf2 = __builtin_amdgcn_fmed3f(e, c1, c2);
  i2 = l1 ? i1 : (l2 ? s : i2);
  i1 = l0 ? i0 : (l1 ? s : i1);
  i0 = l0 ? s : i0;
  c0 = nf0; c1 = nf1; c2 = nf2;
}

// ---------- prep: weights fp32->bf16 + pack xyz2 (one launch) ----------
__global__ __launch_bounds__(256) void k_prep(const float* __restrict__ W0,
                                              const float* __restrict__ W1,
                                              const float* __restrict__ xyz2,
                                              ushort_t* __restrict__ W0b,
                                              ushort_t* __restrict__ W1b,
                                              float4* __restrict__ x2p) {
  int i = blockIdx.x * 256 + threadIdx.x;  // grid 576
  if (i < 98304) {
    W0b[i] = f2bf(W0[i]);
  } else if (i < 131072) {
    W1b[i - 98304] = f2bf(W1[i - 98304]);
  } else {
    int idx = i - 131072;  // 16384
    int b = idx >> 11, s = idx & (S_ - 1);
    const float* base = xyz2 + (size_t)b * 3 * S_;
    float x = base[s], y = base[S_ + s], z = base[2 * S_ + s];
    x2p[idx] = make_float4(x, y, z, 0.5f * (x * x + y * y + z * z));
  }
}

// ---------- transpose points2 [B,256,S] -> p2t bf16 [B,S,256] ----------
__global__ void k_tr_p2(const float* __restrict__ P2, ushort_t* __restrict__ p2t) {
  __shared__ float t[32][33];
  int b = blockIdx.z;
  int s0 = blockIdx.x * 32;
  int c0 = blockIdx.y * 32;
  int tx = threadIdx.x, ty = threadIdx.y;  // (32,8)
#pragma unroll
  for (int j = 0; j < 4; j++) {
    int c = c0 + ty + j * 8;
    t[ty + j * 8][tx] = P2[((size_t)b * D2_ + c) * S_ + s0 + tx];
  }
  __syncthreads();
#pragma unroll
  for (int j = 0; j < 4; j++) {
    int s = s0 + ty + j * 8;
    p2t[((size_t)b * S_ + s) * D2_ + c0 + tx] = f2bf(t[tx][ty + j * 8]);
  }
}

// ---------- transpose points1 [B,128,N] -> Xc cols 0..127 (bf16, row stride 384) ----------
__global__ void k_tr_p1(const float* __restrict__ P1, ushort_t* __restrict__ Xc) {
  __shared__ float t[32][33];
  int b = blockIdx.z;
  int n0 = blockIdx.x * 32;
  int c0 = blockIdx.y * 32;
  int tx = threadIdx.x, ty = threadIdx.y;
#pragma unroll
  for (int j = 0; j < 4; j++) {
    int c = c0 + ty + j * 8;
    t[ty + j * 8][tx] = P1[((size_t)b * D1_ + c) * N_ + n0 + tx];
  }
  __syncthreads();
#pragma unroll
  for (int j = 0; j < 4; j++) {
    int n = n0 + ty + j * 8;
    Xc[((size_t)b * N_ + n) * INCH_ + c0 + tx] = f2bf(t[tx][ty + j * 8]);
  }
}

// ---------- kNN + interpolate: 1024 blocks x 512 threads, 64 queries/block ----------
// Hot loop: packed top-4 keys (f32 d, low 8 mantissa bits = chunk-local idx);
// sorted insert = 4 min/med3, no cmps. Exact recompute + exact ins3 merge after.
__global__ __launch_bounds__(512, 8) void k_knn(const float* __restrict__ xyz1,
                                                const float4* __restrict__ x2p,
                                                const ushort_t* __restrict__ p2t,
                                                ushort_t* __restrict__ Xc) {
  __shared__ float4 xs[8 * 289];     // 36992 B, chunk c at xs + c*289
  __shared__ float wsh[64 * 3];
  __shared__ int   ish[64 * 3];
  int t = threadIdx.x;
  int q0 = blockIdx.x * 64;
  int b = q0 >> 13;
  int n0 = q0 & (N_ - 1);
  for (int l = t; l < S_; l += 512)
    xs[(l >> 8) * 289 + (l & 255)] = x2p[(size_t)b * S_ + l];
  int sub = t & 7;
  int qg = t >> 3;  // [0,64)
  int n = n0 + qg;
  float qx = xyz1[((size_t)b * 3 + 0) * N_ + n];
  float qy = xyz1[((size_t)b * 3 + 1) * N_ + n];
  float qz = xyz1[((size_t)b * 3 + 2) * N_ + n];
  float nrm1 = qx * qx + qy * qy + qz * qz;
  __syncthreads();
  const float4* bp = xs + sub * 289;
  float k0 = 3e38f, k1 = 3e38f, k2 = 3e38f, k3 = 3e38f;
#pragma unroll 4
  for (int i = 0; i < 256; ++i) {
    float4 P = bp[i];
    float e = fmaf(-qx, P.x, fmaf(-qy, P.y, fmaf(-qz, P.z, P.w)));
    float dd = fmaf(2.f, e, nrm1);
    unsigned int kb = (__float_as_uint(dd) & 0xFFFFFF00u) | (unsigned int)i;
    float k = __uint_as_float(kb);
    float n0_ = fminf(k, k0);
    float n1_ = __builtin_amdgcn_fmed3f(k, k0, k1);
    float n2_ = __builtin_amdgcn_fmed3f(k, k1, k2);
    float n3_ = __builtin_amdgcn_fmed3f(k, k2, k3);
    k0 = n0_; k1 = n1_; k2 = n2_; k3 = n3_;
  }
  float ed[4];
  int   si[4];
  {
    float kk[4] = {k0, k1, k2, k3};
#pragma unroll
    for (int c = 0; c < 4; ++c) {
      int loc = (int)(__float_as_uint(kk[c]) & 255u);
      float4 P = bp[loc];
      float e = fmaf(-qx, P.x, fmaf(-qy, P.y, fmaf(-qz, P.z, P.w)));
      ed[c] = fmaf(2.f, e, nrm1);
      si[c] = (sub << 8) + loc;
    }
  }
  float c0 = 3e38f, c1 = 3e38f, c2 = 3e38f;
  int i0 = 0, i1 = 0, i2 = 0;
#pragma unroll
  for (int c = 0; c < 4; ++c) ins3(ed[c], si[c], c0, c1, c2, i0, i1, i2);
#pragma unroll
  for (int d = 1; d < 8; d <<= 1) {
    float e0 = __shfl_xor(c0, d); int s0 = __shfl_xor(i0, d);
    float e1 = __shfl_xor(c1, d); int s1 = __shfl_xor(i1, d);
    float e2 = __shfl_xor(c2, d); int s2 = __shfl_xor(i2, d);
    ins3(e0, s0, c0, c1, c2, i0, i1, i2);
    ins3(e1, s1, c0, c1, c2, i0, i1, i2);
    ins3(e2, s2, c0, c1, c2, i0, i1, i2);
  }
  if (sub == 0) {
    float r0 = 1.f / (c0 + 1e-8f);
    float r1 = 1.f / (c1 + 1e-8f);
    float r2 = 1.f / (c2 + 1e-8f);
    float rs = 1.f / (r0 + r1 + r2);
    wsh[qg * 3 + 0] = r0 * rs; wsh[qg * 3 + 1] = r1 * rs; wsh[qg * 3 + 2] = r2 * rs;
    ish[qg * 3 + 0] = i0; ish[qg * 3 + 1] = i1; ish[qg * 3 + 2] = i2;
  }
  __syncthreads();
  int lane = t & 63, grp = t >> 6;
  size_t sbase2 = (size_t)b * S_;
#pragma unroll 2
  for (int it = 0; it < 8; ++it) {
    int ql = it * 8 + grp;
    int q = q0 + ql;
    float w0 = wsh[ql * 3 + 0], w1 = wsh[ql * 3 + 1], w2 = wsh[ql * 3 + 2];
    int j0 = ish[ql * 3 + 0], j1 = ish[ql * 3 + 1], j2 = ish[ql * 3 + 2];
    ushort4 a0 = *(const ushort4*)&p2t[(sbase2 + j0) * D2_ + lane * 4];
    ushort4 a1 = *(const ushort4*)&p2t[(sbase2 + j1) * D2_ + lane * 4];
    ushort4 a2 = *(const ushort4*)&p2t[(sbase2 + j2) * D2_ + lane * 4];
    ushort4 o;
    o.x = f2bf(w0 * bf2f(a0.x) + w1 * bf2f(a1.x) + w2 * bf2f(a2.x));
    o.y = f2bf(w0 * bf2f(a0.y) + w1 * bf2f(a1.y) + w2 * bf2f(a2.y));
    o.z = f2bf(w0 * bf2f(a0.z) + w1 * bf2f(a1.z) + w2 * bf2f(a2.z));
    o.w = f2bf(w0 * bf2f(a0.w) + w1 * bf2f(a1.w) + w2 * bf2f(a2.w));
    *(ushort4*)&Xc[(size_t)q * INCH_ + D1_ + lane * 4] = o;
  }
}

// ---------- generic column reduction of per-block partials ----------
// grid = ncols blocks; block 256 threads; partials layout [row][col].
__global__ __launch_bounds__(256) void k_redstats(const float* __restrict__ ps,
                                                  const float* __restrict__ pq,
                                                  float* __restrict__ sum,
                                                  float* __restrict__ ssq,
                                                  int ncols, int nrows) {
  __shared__ float ls[4], lq[4];
  int col = blockIdx.x;
  int t = threadIdx.x;
  float s = 0.f, q = 0.f;
  for (int r = t; r < nrows; r += 256) {
    s += ps[(size_t)r * ncols + col];
    q += pq[(size_t)r * ncols + col];
  }
#pragma unroll
  for (int d = 1; d < 64; d <<= 1) {
    s += __shfl_xor(s, d);
    q += __shfl_xor(q, d);
  }
  if ((t & 63) == 0) { ls[t >> 6] = s; lq[t >> 6] = q; }
  __syncthreads();
  if (t == 0) {
    sum[col] = ls[0] + ls[1] + ls[2] + ls[3];
    ssq[col] = lq[0] + lq[1] + lq[2] + lq[3];
  }
}

// ---------- GEMM1: Y1b[M,256](bf16) = Xc[M,384] * W0b[256,384]^T, 128x256 tile ----------
// BN stats: NO atomics — per-block partial row, coalesced store. (atomic
// serialization on 8 cache lines was ~60us; see R5 post-mortem)
__global__ __launch_bounds__(512) void k_gemm1(const ushort_t* __restrict__ A,
                                               const ushort_t* __restrict__ Bw,
                                               ushort_t* __restrict__ Cc,
                                               float* __restrict__ psum,
                                               float* __restrict__ pssq) {
  __shared__ __align__(16) ushort_t As[128 * 32];
  __shared__ __align__(16) ushort_t Bs[256 * 32];
  __shared__ float red_s[2][256], red_q[2][256];
  const int tid = threadIdx.x;
  const int m0 = blockIdx.x * 128;
  const int wave = tid >> 6;
  const int wuni = __builtin_amdgcn_readfirstlane(wave);  // 0..7
  const int lane = tid & 63;
  const int quad = lane >> 4;
  const int l16 = lane & 15;
  const int wrow = (wave >> 2) * 64;   // 2 row-waves
  const int wcol = (wave & 3) * 64;    // 4 col-waves
  const int arow = tid >> 2, aseg = tid & 3;
  floatx4 acc[4][4];
#pragma unroll
  for (int i = 0; i < 4; i++)
#pragma unroll
    for (int j = 0; j < 4; j++) acc[i][j] = (floatx4){0.f, 0.f, 0.f, 0.f};

  for (int k0 = 0; k0 < INCH_; k0 += 32) {
    ASYNC_CP16(&A[(size_t)(m0 + arow) * INCH_ + k0 + aseg * 8], &As[wuni * 512]);
#pragma unroll
    for (int it = 0; it < 2; it++) {
      int l = tid + it * 512;
      int row = l >> 2, seg = l & 3;
      ASYNC_CP16(&Bw[(size_t)row * INCH_ + k0 + seg * 8], &Bs[it * 4096 + wuni * 512]);
    }
    __syncthreads();
    bf16x8 af[4], bfr[4];
#pragma unroll
    for (int mt = 0; mt < 4; mt++) af[mt] = *(const bf16x8*)&As[(wrow + mt * 16 + l16) * 32 + quad * 8];
#pragma unroll
    for (int nt = 0; nt < 4; nt++) bfr[nt] = *(const bf16x8*)&Bs[(wcol + nt * 16 + l16) * 32 + quad * 8];
#pragma unroll
    for (int mt = 0; mt < 4; mt++)
#pragma unroll
      for (int nt = 0; nt < 4; nt++)
        acc[mt][nt] = __builtin_amdgcn_mfma_f32_16x16x32_bf16(af[mt], bfr[nt], acc[mt][nt], 0, 0, 0);
    __syncthreads();
  }
#pragma unroll
  for (int mt = 0; mt < 4; mt++) {
#pragma unroll
    for (int i = 0; i < 4; i++) {
      int row = m0 + wrow + mt * 16 + quad * 4 + i;
#pragma unroll
      for (int nt = 0; nt < 4; nt++) {
        int col = wcol + nt * 16 + l16;
        Cc[(size_t)row * 256 + col] = f2bf(acc[mt][nt][i]);
      }
    }
  }
  // BN stats partials (f32): shfl reduce -> LDS cross-row-wave -> coalesced store
#pragma unroll
  for (int nt = 0; nt < 4; nt++) {
    float s = 0.f, s2 = 0.f;
#pragma unroll
    for (int mt = 0; mt < 4; mt++)
#pragma unroll
      for (int i = 0; i < 4; i++) {
        float v = acc[mt][nt][i];
        s += v;
        s2 = fmaf(v, v, s2);
      }
    s += __shfl_xor(s, 16);  s2 += __shfl_xor(s2, 16);
    s += __shfl_xor(s, 32);  s2 += __shfl_xor(s2, 32);
    if (quad == 0) {
      int col = wcol + nt * 16 + l16;
      red_s[wave >> 2][col] = s;
      red_q[wave >> 2][col] = s2;
    }
  }
  __syncthreads();
  if (tid < 256) {
    psum[(size_t)blockIdx.x * 256 + tid] = red_s[0][tid] + red_s[1][tid];
    pssq[(size_t)blockIdx.x * 256 + tid] = red_q[0][tid] + red_q[1][tid];
  }
}

// ---------- GEMM2 + BN1 partials + TRANSPOSED Y2 write ----------
// 1024 blocks x 256 thr, 64x128 tile, 4 waves (2 row x 2 col, each 32x64).
// Writes Y2t[b*128+c][n] bf16; BN1 stats via partials (no atomics).
__global__ __launch_bounds__(256, 4) void k_gemm2t(const ushort_t* __restrict__ Y1,
                                                   const ushort_t* __restrict__ Bw,
                                                   const float* __restrict__ sum0,
                                                   const float* __restrict__ ssq0,
                                                   const float* __restrict__ g0,
                                                   const float* __restrict__ be0,
                                                   ushort_t* __restrict__ Y2t,
                                                   float* __restrict__ psum,
                                                   float* __restrict__ pssq) {
  // union: GEMM staging (As 4K + Bs 8K) overlaid with transpose buf tb[64][129] f32
  __shared__ __align__(16) char ubuf[64 * 129 * 4];  // 33024 B
  __shared__ float scs[256], shs[256];
  __shared__ float red_s[2][128], red_q[2][128];
  ushort_t* As = (ushort_t*)ubuf;
  ushort_t* Bs = (ushort_t*)(ubuf + 4096);
  float* tb = (float*)ubuf;
  const int tid = threadIdx.x;
  const int m0 = blockIdx.x * 64;
  const int b = m0 >> 13;
  const int n0 = m0 & (N_ - 1);
  const int wave = tid >> 6;
  const int wuni = __builtin_amdgcn_readfirstlane(wave);  // 0..3
  const int lane = tid & 63;
  const int quad = lane >> 4;
  const int l16 = lane & 15;
  const int wrow = (wave >> 1) * 32;   // 2 row-waves of 32
  const int wcol = (wave & 1) * 64;    // 2 col-waves of 64
  {
    float mean = sum0[tid] * (1.f / 65536.f);
    float var = ssq0[tid] * (1.f / 65536.f) - mean * mean;
    float sc = rsqrtf(var + 1e-5f) * g0[tid];
    scs[tid] = sc;
    shs[tid] = be0[tid] - mean * sc;
  }
  floatx4 acc[2][4];
#pragma unroll
  for (int i = 0; i < 2; i++)
#pragma unroll
    for (int j = 0; j < 4; j++) acc[i][j] = (floatx4){0.f, 0.f, 0.f, 0.f};
  __syncthreads();

  const int arow = tid >> 2, aseg = tid & 3;  // A: 64 rows x 4 segs
  for (int k0 = 0; k0 < 256; k0 += 32) {
    // B tile async: 128x32 = 512 lane-loads (2 its)
#pragma unroll
    for (int it = 0; it < 2; it++) {
      int l = tid + it * 256;
      int row = l >> 2, seg = l & 3;
      ASYNC_CP16(&Bw[(size_t)row * 256 + k0 + seg * 8], &Bs[it * 2048 + wuni * 512]);
    }
    // A tile: BN0+relu transform on the fly (64 rows x 32 k)
    {
      ushort4 y01 = *(const ushort4*)&Y1[(size_t)(m0 + arow) * 256 + k0 + aseg * 8];
      ushort4 y23 = *(const ushort4*)&Y1[(size_t)(m0 + arow) * 256 + k0 + aseg * 8 + 4];
      int c = k0 + aseg * 8;
      ushort4 o0, o1;
      o0.x = f2bf(fmaxf(fmaf(bf2f(y01.x), scs[c + 0], shs[c + 0]), 0.f));
      o0.y = f2bf(fmaxf(fmaf(bf2f(y01.y), scs[c + 1], shs[c + 1]), 0.f));
      o0.z = f2bf(fmaxf(fmaf(bf2f(y01.z), scs[c + 2], shs[c + 2]), 0.f));
      o0.w = f2bf(fmaxf(fmaf(bf2f(y01.w), scs[c + 3], shs[c + 3]), 0.f));
      o1.x = f2bf(fmaxf(fmaf(bf2f(y23.x), scs[c + 4], shs[c + 4]), 0.f));
      o1.y = f2bf(fmaxf(fmaf(bf2f(y23.y), scs[c + 5], shs[c + 5]), 0.f));
      o1.z = f2bf(fmaxf(fmaf(bf2f(y23.z), scs[c + 6], shs[c + 6]), 0.f));
      o1.w = f2bf(fmaxf(fmaf(bf2f(y23.w), scs[c + 7], shs[c + 7]), 0.f));
      *(ushort4*)&As[arow * 32 + aseg * 8] = o0;
      *(ushort4*)&As[arow * 32 + aseg * 8 + 4] = o1;
    }
    __syncthreads();
    bf16x8 af[2], bfr[4];
#pragma unroll
    for (int mt = 0; mt < 2; mt++) af[mt] = *(const bf16x8*)&As[(wrow + mt * 16 + l16) * 32 + quad * 8];
#pragma unroll
    for (int nt = 0; nt < 4; nt++) bfr[nt] = *(const bf16x8*)&Bs[(wcol + nt * 16 + l16) * 32 + quad * 8];
#pragma unroll
    for (int mt = 0; mt < 2; mt++)
#pragma unroll
      for (int nt = 0; nt < 4; nt++)
        acc[mt][nt] = __builtin_amdgcn_mfma_f32_16x16x32_bf16(af[mt], bfr[nt], acc[mt][nt], 0, 0, 0);
    __syncthreads();
  }
  // BN1 stats partials (each wave covers 32 rows x 64 cols)
#pragma unroll
  for (int nt = 0; nt < 4; nt++) {
    float s = 0.f, s2 = 0.f;
#pragma unroll
    for (int mt = 0; mt < 2; mt++)
#pragma unroll
      for (int i = 0; i < 4; i++) {
        float v = acc[mt][nt][i];
        s += v;
        s2 = fmaf(v, v, s2);
      }
    s += __shfl_xor(s, 16);  s2 += __shfl_xor(s2, 16);
    s += __shfl_xor(s, 32);  s2 += __shfl_xor(s2, 32);
    if (quad == 0) {
      int col = wcol + nt * 16 + l16;
      red_s[wave >> 1][col] = s;
      red_q[wave >> 1][col] = s2;
    }
  }
  // stage raw acc f32 -> tb (4 waves, disjoint 32x64 regions)
#pragma unroll
  for (int mt = 0; mt < 2; mt++)
#pragma unroll
    for (int i = 0; i < 4; i++) {
      int rl = wrow + mt * 16 + quad * 4 + i;  // 0..63
#pragma unroll
      for (int nt = 0; nt < 4; nt++) {
        int col = wcol + nt * 16 + l16;
        tb[rl * 129 + col] = acc[mt][nt][i];
      }
    }
  __syncthreads();
  if (tid < 128) {
    psum[(size_t)blockIdx.x * 128 + tid] = red_s[0][tid] + red_s[1][tid];
    pssq[(size_t)blockIdx.x * 128 + tid] = red_q[0][tid] + red_q[1][tid];
  }
  // transposed write: Y2t[(b*128+c)*N + n0 + j], ushort4 (4 n's per store)
#pragma unroll
  for (int it = 0; it < 8; ++it) {
    int idx = it * 256 + tid;        // [0,2048)
    int c = idx >> 4;                // channel 0..127
    int j4 = (idx & 15) * 4;         // n offset 0..60
    ushort4 v;
    v.x = f2bf(tb[(j4 + 0) * 129 + c]);
    v.y = f2bf(tb[(j4 + 1) * 129 + c]);
    v.z = f2bf(tb[(j4 + 2) * 129 + c]);
    v.w = f2bf(tb[(j4 + 3) * 129 + c]);
    *(ushort4*)&Y2t[((size_t)(b * 128 + c)) * N_ + n0 + j4] = v;
  }
}

// ---------- finalize: BN1 + relu, pure streaming (Y2t bf16 -> out f32) ----------
__global__ __launch_bounds__(256) void k_out2(const ushort_t* __restrict__ Y2t,
                                              const float* __restrict__ sum1,
                                              const float* __restrict__ ssq1,
                                              const float* __restrict__ g1,
                                              const float* __restrict__ be1,
                                              float* __restrict__ out) {
  __shared__ float sc1[128], sh1[128];
  int tid = threadIdx.x;
  if (tid < 128) {
    float mean = sum1[tid] * (1.f / 65536.f);
    float var = ssq1[tid] * (1.f / 65536.f) - mean * mean;
    float sc = rsqrtf(var + 1e-5f) * g1[tid];
    sc1[tid] = sc;
    sh1[tid] = be1[tid] - mean * sc;
  }
  __syncthreads();
#pragma unroll
  for (int it = 0; it < 4; ++it) {
    int fid = (it * 2048 + blockIdx.x) * 256 + tid;   // [0, 2^21)
    int r = fid >> 11;            // row 0..1023 (b*128+c)
    int c = r & 127;
    int n4 = (fid & 2047) * 4;
    ushort4 y = *(const ushort4*)&Y2t[((size_t)r << 13) + n4];
    float sc = sc1[c], sh = sh1[c];
    float4 v;
    v.x = fmaxf(fmaf(bf2f(y.x), sc, sh), 0.f);
    v.y = fmaxf(fmaf(bf2f(y.y), sc, sh), 0.f);
    v.z = fmaxf(fmaf(bf2f(y.z), sc, sh), 0.f);
    v.w = fmaxf(fmaf(bf2f(y.w), sc, sh), 0.f);
    *(float4*)&out[((size_t)r << 13) + n4] = v;
  }
}

extern "C" void kernel_launch(void* const* d_in, const int* in_sizes, int n_in,
                              void* d_out, int out_size, void* d_ws, size_t ws_size,
                              hipStream_t stream) {
  const float* xyz1    = (const float*)d_in[0];
  const float* xyz2    = (const float*)d_in[1];
  const float* points1 = (const float*)d_in[2];
  const float* points2 = (const float*)d_in[3];
  const float* W0 = (const float*)d_in[4];
  const float* g0 = (const float*)d_in[6];
  const float* be0 = (const float*)d_in[7];
  const float* W1 = (const float*)d_in[8];
  const float* g1 = (const float*)d_in[10];
  const float* be1 = (const float*)d_in[11];
  float* out = (float*)d_out;
  char* ws = (char*)d_ws;

  float* sum0   = (float*)(ws + OFF_STATS);
  float* ssq0   = sum0 + 256;
  float* sum1   = sum0 + 512;
  float* ssq1   = sum0 + 640;
  ushort_t* W0b = (ushort_t*)(ws + OFF_W0B);
  ushort_t* W1b = (ushort_t*)(ws + OFF_W1B);
  float4* x2p   = (float4*)(ws + OFF_X2P);
  ushort_t* p2t = (ushort_t*)(ws + OFF_P2T);
  ushort_t* Xc  = (ushort_t*)(ws + OFF_XC);
  ushort_t* Y1b = (ushort_t*)(ws + OFF_Y1);
  ushort_t* Y2t = (ushort_t*)(ws + OFF_XC);  // overlays Xc (dead after GEMM1)
  float* psum0  = (float*)(ws + OFF_PS0);    // overlay p2t (dead after k_knn)
  float* pssq0  = (float*)(ws + OFF_PQ0);
  float* psum1  = (float*)(ws + OFF_PS1);
  float* pssq1  = (float*)(ws + OFF_PQ1);

  k_prep<<<576, 256, 0, stream>>>(W0, W1, xyz2, W0b, W1b, x2p);
  k_tr_p2<<<dim3(64, 8, 8), dim3(32, 8), 0, stream>>>(points2, p2t);
  k_tr_p1<<<dim3(256, 4, 8), dim3(32, 8), 0, stream>>>(points1, Xc);
  k_knn<<<1024, 512, 0, stream>>>(xyz1, x2p, p2t, Xc);
  k_gemm1<<<512, 512, 0, stream>>>(Xc, W0b, Y1b, psum0, pssq0);
  k_redstats<<<256, 256, 0, stream>>>(psum0, pssq0, sum0, ssq0, 256, 512);
  k_gemm2t<<<1024, 256, 0, stream>>>(Y1b, W1b, sum0, ssq0, g0, be0,
                                     Y2t, psum1, pssq1);
  k_redstats<<<128, 256, 0, stream>>>(psum1, pssq1, sum1, ssq1, 128, 1024);
  k_out2<<<2048, 256, 0, stream>>>(Y2t, sum1, ssq1, g1, be1, out);
}